// Round 9
// baseline (445.975 us; speedup 1.0000x reference)
//
#include <hip/hip_runtime.h>
#include <stdint.h>

// WASLL R13: inverse-permutation scatter pipeline -- the 3-pass sort was
// solving a problem the input doesn't have. flat_netpin is a PERMUTATION
// (harness-guarded NP==4*N uniform CSR), so:
//   P1': inv[fnp[k]] = k          (linear read, 4B scatter over 32MB)
//   P2': ent3[inv[pin]] = pos[pin].y  (ALL reads linear -- inv and pos share
//        the pin index; 4B scatter; no LDS/hist/scan/atomic machinery at all)
//   P3': per net j read ent3[4j..4j+3] as float4 (coalesced), wa4, reduce.
// Eliminates: both counting sorts, all LDS windows, all cursor atomics,
// 2 dispatches, and every random READ. Only irregular traffic is
// fire-and-forget 4B scattered writes; each ent3/inv byte written exactly
// once (permutation) so L2/L3 byte-masked merging yields ~32MB HBM writeback.
// R12 accounting: p2=62.6us but p1+p3+gaps ~207us of sort machinery; traffic
// floor of this formulation is ~230MB ~ 37us. Fallback path unchanged.

#define NTHR 1024
#define GRID_CAP 2048

__device__ __forceinline__ float wa4(float a, float b, float c, float d, float ig) {
    float ea = __expf(a * ig), eb = __expf(b * ig);
    float ec = __expf(c * ig), ed = __expf(d * ig);
    float na = __expf(-a * ig), nb = __expf(-b * ig);
    float nc = __expf(-c * ig), nd = __expf(-d * ig);
    float s_ep  = ea + eb + ec + ed;
    float s_xep = a * ea + b * eb + c * ec + d * ed;
    float s_en  = na + nb + nc + nd;
    float s_xen = a * na + b * nb + c * nc + d * nd;
    return s_xep / s_ep - s_xen / s_en;
}

// ---------------- P1': build inverse permutation ----------------
__global__ __launch_bounds__(NTHR) void p1_scatter(
    const int4* __restrict__ fnp4, int NP4,
    unsigned* __restrict__ inv, float* __restrict__ out)
{
    const int tid = blockIdx.x * blockDim.x + threadIdx.x;
    if (tid == 0) out[0] = 0.0f;                 // stream-ordered before p3
    const int stride = gridDim.x * blockDim.x;
    for (int i = tid; i < NP4; i += stride) {
        int4 v = fnp4[i];                        // coalesced 16B read
        unsigned k = (unsigned)(4 * i);
        inv[(unsigned)v.x] = k;                  // 4B scatters (permutation:
        inv[(unsigned)v.y] = k + 1;              //  every slot written once)
        inv[(unsigned)v.z] = k + 2;
        inv[(unsigned)v.w] = k + 3;
    }
}

// ---------------- P2': deliver coords to CSR slots ----------------
// inv and pos are BOTH indexed by pin -> all reads coalesced.
__global__ __launch_bounds__(NTHR) void p2_scatter(
    const unsigned* __restrict__ inv, const float4* __restrict__ pos4,
    const int* __restrict__ slrx_p, const int* __restrict__ slry_p,
    int NP, float* __restrict__ e3x, float* __restrict__ e3y)
{
    const bool dx = slrx_p[0] > 1, dy = slry_p[0] > 1;
    if (!dx && !dy) return;
    const unsigned np = (unsigned)NP;
    const int tid = blockIdx.x * blockDim.x + threadIdx.x;
    const int stride = gridDim.x * blockDim.x;
    const int NP4 = NP >> 2;
    const uint4* inv4 = (const uint4*)inv;
    for (int i = tid; i < NP4; i += stride) {
        uint4  kk = inv4[i];                     // coalesced 16B read
        float4 a  = pos4[2 * i];                 // pins 4i,4i+1: x0,y0,x1,y1
        float4 b  = pos4[2 * i + 1];             // pins 4i+2,4i+3: x2,y2,x3,y3
        if (dy) {                                // scattered 4B stores
            if (kk.x < np) e3y[kk.x] = a.y;
            if (kk.y < np) e3y[kk.y] = a.w;
            if (kk.z < np) e3y[kk.z] = b.y;
            if (kk.w < np) e3y[kk.w] = b.w;
        }
        if (dx) {
            if (kk.x < np) e3x[kk.x] = a.x;
            if (kk.y < np) e3x[kk.y] = a.z;
            if (kk.z < np) e3x[kk.z] = b.x;
            if (kk.w < np) e3x[kk.w] = b.z;
        }
    }
}

// ---------------- P3': per-net wa4 + global reduce ----------------
__global__ __launch_bounds__(NTHR) void p3_eval(
    const float* __restrict__ e3x, const float* __restrict__ e3y,
    const float* __restrict__ wts, const float* __restrict__ ig_p,
    const int* __restrict__ slrx_p, const int* __restrict__ slry_p,
    int N, float* __restrict__ out)
{
    const bool dx = slrx_p[0] > 1, dy = slry_p[0] > 1;
    if (!dx && !dy) return;                      // out already zeroed by p1
    const float ig = ig_p[0];
    const int tid = blockIdx.x * blockDim.x + threadIdx.x;
    const int stride = gridDim.x * blockDim.x;
    const float4* x4 = (const float4*)e3x;
    const float4* y4 = (const float4*)e3y;

    float val = 0.0f;
    for (int j = tid; j < N; j += stride) {
        float s = 0.0f;
        if (dy) { float4 p = y4[j]; s += wa4(p.x, p.y, p.z, p.w, ig); }
        if (dx) { float4 p = x4[j]; s += wa4(p.x, p.y, p.z, p.w, ig); }
        val += wts[j] * s;                       // coalesced float4 + scalar
    }

    #pragma unroll
    for (int off = 32; off > 0; off >>= 1) val += __shfl_down(val, off, 64);
    __shared__ float smem[NTHR / 64];
    if ((threadIdx.x & 63) == 0) smem[threadIdx.x >> 6] = val;
    __syncthreads();
    if (threadIdx.x == 0) {
        float s = 0.0f;
        #pragma unroll
        for (int w = 0; w < NTHR / 64; ++w) s += smem[w];
        atomicAdd(out, s);
    }
}

// ---------------- fallback: proven R1 gather kernel ----------------
__global__ __launch_bounds__(256) void wasll_fallback(
    const float2* __restrict__ pos, const int4* __restrict__ fnp4,
    const float* __restrict__ net_weights, const float* __restrict__ inv_gamma_p,
    const int* __restrict__ slrx_p, const int* __restrict__ slry_p,
    float* __restrict__ out, int num_nets)
{
    const float ig = inv_gamma_p[0];
    const float dx = (slrx_p[0] > 1) ? 1.0f : 0.0f;
    const float dy = (slry_p[0] > 1) ? 1.0f : 0.0f;
    int net = blockIdx.x * blockDim.x + threadIdx.x;
    float val = 0.0f;
    if (net < num_nets) {
        int4 idx = fnp4[net];
        float2 p0 = pos[idx.x], p1 = pos[idx.y], p2 = pos[idx.z], p3 = pos[idx.w];
        val = net_weights[net] * (dx * wa4(p0.x, p1.x, p2.x, p3.x, ig)
                                + dy * wa4(p0.y, p1.y, p2.y, p3.y, ig));
    }
    #pragma unroll
    for (int off = 32; off > 0; off >>= 1) val += __shfl_down(val, off, 64);
    __shared__ float smem[4];
    if ((threadIdx.x & 63) == 0) smem[threadIdx.x >> 6] = val;
    __syncthreads();
    if (threadIdx.x == 0)
        atomicAdd(out, smem[0] + smem[1] + smem[2] + smem[3]);
}

__global__ void zero_out_kernel(float* __restrict__ out) { out[0] = 0.0f; }

extern "C" void kernel_launch(void* const* d_in, const int* in_sizes, int n_in,
                              void* d_out, int out_size, void* d_ws, size_t ws_size,
                              hipStream_t stream) {
    const float* posf        = (const float*)d_in[0];
    const int*   fnp         = (const int*)d_in[1];
    const float* net_weights = (const float*)d_in[4];
    const float* inv_gamma   = (const float*)d_in[7];
    const int*   slrx        = (const int*)d_in[8];
    const int*   slry        = (const int*)d_in[9];
    float*       out         = (float*)d_out;
    const int    N  = in_sizes[4];
    const int    NP = in_sizes[1];

    size_t off = 0;
    auto carve = [&](size_t bytes) { size_t o = off; off += (bytes + 255) & ~size_t(255); return o; };
    size_t o_inv = carve((size_t)NP * sizeof(unsigned));
    size_t o_e3x = carve((size_t)NP * sizeof(float));
    size_t o_e3y = carve((size_t)NP * sizeof(float));

    const bool ok = (NP == 4 * N) && (NP % 4 == 0) && (off <= ws_size);
    if (!ok) {
        hipLaunchKernelGGL(zero_out_kernel, dim3(1), dim3(1), 0, stream, out);
        const int block = 256, grid = (N + block - 1) / block;
        hipLaunchKernelGGL(wasll_fallback, dim3(grid), dim3(block), 0, stream,
                           (const float2*)posf, (const int4*)fnp, net_weights,
                           inv_gamma, slrx, slry, out, N);
        return;
    }

    char* ws = (char*)d_ws;
    unsigned* inv = (unsigned*)(ws + o_inv);
    float*    e3x = (float*)(ws + o_e3x);
    float*    e3y = (float*)(ws + o_e3y);

    const int NP4 = NP >> 2;
    int g12 = (NP4 + NTHR - 1) / NTHR; if (g12 > GRID_CAP) g12 = GRID_CAP;
    int g3  = (N   + NTHR - 1) / NTHR; if (g3  > GRID_CAP) g3  = GRID_CAP;

    hipLaunchKernelGGL(p1_scatter, dim3(g12), dim3(NTHR), 0, stream,
                       (const int4*)fnp, NP4, inv, out);
    hipLaunchKernelGGL(p2_scatter, dim3(g12), dim3(NTHR), 0, stream,
                       inv, (const float4*)posf, slrx, slry, NP, e3x, e3y);
    hipLaunchKernelGGL(p3_eval, dim3(g3), dim3(NTHR), 0, stream,
                       e3x, e3y, net_weights, inv_gamma, slrx, slry, N, out);
}

// Round 10
// 290.950 us; speedup vs baseline: 1.5328x; 1.5328x over previous
//
#include <hip/hip_runtime.h>
#include <stdint.h>

// WASLL R14: whole-pipeline fusion into ONE persistent kernel.
// R13 post-mortem: random 4B scatters to HBM writeback at 32B granule ->
// 8x write amplification (258MB for 32MB useful), 150us/pass. Scatter
// pipeline dead; R12 (269.7us) stands. R12 accounting: kernels ~185us,
// inter-dispatch gaps ~85us (R11->R12 delta: ~17us/dispatch boundary).
// R14 removes the boundaries: p1/p2/p3 as phases of one 512-block x 512-thread
// persistent kernel with software grid barriers.
//   - residency proof: LDS = max(76KB p1, 70KB p2, 64KB p3) = 76KB -> exactly
//     2 blocks/CU x 256 CU = 512 blocks co-resident; __launch_bounds__(512,4)
//     caps VGPR at 128 (phase bodies proven 52-56).
//   - barrier: monotonic ticket counter, target = next multiple of 512;
//     __threadfence() release/acquire (agent scope handles cross-XCD L2).
//     Bench path (y-only) = 2 passages.
//   - cursor arrays need NO init: every bucket fills exactly (permutation +
//     NP%JB_SIZE==0 guard), so masking the raw cursor by bucket size turns
//     any garbage base into a harmless rotation of slot assignments. Only
//     the 256B barrier counter is memset. 2 dispatches total (was 5-6).
// Phase bodies are R8/R12-proven verbatim (512t, 16-deep, win/staged alias).

#define PINB_SHIFT 13
#define PINB_SIZE  (1 << PINB_SHIFT)      // 8192 pins/bucket = 32KB window
#define MAX_PINB   1024
#define JB_SHIFT   14
#define JB_SIZE    (1 << JB_SHIFT)        // 16384 slots/j-bucket (4096 nets)
#define MAX_JB     512
#define NTHR2      512                    // block size
#define NBLK       512                    // grid size (2 blocks/CU x 256 CU)

__device__ __forceinline__ float wa4(float a, float b, float c, float d, float ig) {
    float ea = __expf(a * ig), eb = __expf(b * ig);
    float ec = __expf(c * ig), ed = __expf(d * ig);
    float na = __expf(-a * ig), nb = __expf(-b * ig);
    float nc = __expf(-c * ig), nd = __expf(-d * ig);
    float s_ep  = ea + eb + ec + ed;
    float s_xep = a * ea + b * eb + c * ec + d * ed;
    float s_en  = na + nb + nc + nd;
    float s_xen = a * na + b * nb + c * nc + d * nd;
    return s_xep / s_ep - s_xen / s_en;
}

// monotonic-ticket grid barrier: bar memset to 0 each run; each passage
// advances the counter by NBLK. threadfence = agent-scope release/acquire.
__device__ __forceinline__ void grid_bar(unsigned* bar) {
    __syncthreads();                       // all block mem-ops issued+acked
    if (threadIdx.x == 0) {
        __threadfence();                   // release: writeback this XCD's L2
        unsigned tkt = atomicAdd(bar, 1u);
        unsigned tgt = (tkt / NBLK + 1u) * (unsigned)NBLK;
        while (atomicMax(bar, 0u) < tgt)   // coherent read (no modify)
            __builtin_amdgcn_s_sleep(4);
        __threadfence();                   // acquire: invalidate stale lines
    }
    __syncthreads();
}

__global__ __launch_bounds__(NTHR2, 4) void fused_wasll(
    const int4* __restrict__ fnp4, const float2* __restrict__ pos2,
    const float* __restrict__ wts, const float* __restrict__ ig_p,
    const int* __restrict__ slrx_p, const int* __restrict__ slry_p,
    int NP, int n_pinb, int n_jb,
    uint2* __restrict__ ent1, uint2* __restrict__ ent2a,
    uint2* __restrict__ ent2b,
    unsigned* __restrict__ cur1, unsigned* __restrict__ cur2,
    unsigned* __restrict__ bar, float* __restrict__ out)
{
    __shared__ __align__(16) char smem[PINB_SIZE * sizeof(uint2) + 3 * MAX_PINB * 4]; // 76KB
    const int t = threadIdx.x;
    const bool dx = slrx_p[0] > 1, dy = slry_p[0] > 1;

    if (blockIdx.x == 0 && t == 0) out[0] = 0.0f;
    if (!dx && !dy) return;                // uniform: no barriers executed

    // ---------------- phase A: partition (pin, k) by pin-bucket ----------------
    {
        uint2*    staged = (uint2*)smem;                                 // 64KB
        unsigned* hist   = (unsigned*)(smem + PINB_SIZE * sizeof(uint2));// 4KB
        unsigned* scn    = hist + MAX_PINB;                              // 4KB
        unsigned* gbase  = scn + MAX_PINB;                               // 4KB
        for (int c = blockIdx.x; c < n_pinb; c += NBLK) {                // ~2 chunks
            const int base = c << PINB_SHIFT;                            // full chunk
            for (int b = t; b < MAX_PINB; b += NTHR2) hist[b] = 0;
            __syncthreads();

            unsigned pin[16], rnk[16];
            #pragma unroll
            for (int m4 = 0; m4 < 4; ++m4) {
                int4 v = fnp4[(base >> 2) + t + NTHR2 * m4];             // coalesced
                pin[4*m4+0] = (unsigned)v.x; pin[4*m4+1] = (unsigned)v.y;
                pin[4*m4+2] = (unsigned)v.z; pin[4*m4+3] = (unsigned)v.w;
            }
            #pragma unroll
            for (int i = 0; i < 16; ++i)
                rnk[i] = atomicAdd(&hist[pin[i] >> PINB_SHIFT], 1u);
            __syncthreads();

            if (t < 64) {                  // wave-0 scan, 16 buckets/lane
                unsigned v[16], s = 0;
                #pragma unroll
                for (int i = 0; i < 16; ++i) { v[i] = hist[t * 16 + i]; s += v[i]; }
                unsigned e = s;
                #pragma unroll
                for (int off = 1; off < 64; off <<= 1) {
                    unsigned u = __shfl_up(e, off, 64);
                    if (t >= off) e += u;
                }
                e -= s;
                #pragma unroll
                for (int i = 0; i < 16; ++i) { scn[t * 16 + i] = e; e += v[i]; }
            }
            __syncthreads();

            // all-thread cursor atomics; RAW result (garbage-rotation safe)
            for (int b = t; b < n_pinb; b += NTHR2)
                if (hist[b]) gbase[b] = atomicAdd(&cur1[b], hist[b]);
            __syncthreads();

            #pragma unroll
            for (int m4 = 0; m4 < 4; ++m4)
                #pragma unroll
                for (int cc = 0; cc < 4; ++cc) {
                    int i = 4 * m4 + cc;
                    unsigned kk = (unsigned)(base + 4 * (t + NTHR2 * m4) + cc);
                    staged[scn[pin[i] >> PINB_SHIFT] + rnk[i]] =
                        make_uint2(pin[i], kk);
                }
            __syncthreads();

            for (int k = t; k < PINB_SIZE; k += NTHR2) {   // coalesced runs
                uint2 e = staged[k];
                unsigned b = e.x >> PINB_SHIFT;
                unsigned slot = (gbase[b] + ((unsigned)k - scn[b])) & (PINB_SIZE - 1);
                ent1[((size_t)b << PINB_SHIFT) + slot] = e;
            }
            __syncthreads();               // staged reads done before next iter
        }
    }
    grid_bar(bar);

    // ---------------- per-dim: phase B (gather+bin) then phase C (eval) ----------------
    for (int d = 0; d < 2; ++d) {
        const bool act = d ? dy : dx;
        if (!act) continue;
        uint2* ent2d = d ? ent2b : ent2a;
        if (d == 1 && dx) grid_bar(bar);   // C(d0) readers done before B(d1) writes

        // phase B
        {
            float*    win    = (float*)smem;                                  // 32KB
            uint2*    staged = (uint2*)smem;                                  // 64KB
            unsigned* hist   = (unsigned*)(smem + PINB_SIZE * sizeof(uint2)); // 2KB
            unsigned* scn    = hist + MAX_JB;                                 // 2KB
            unsigned* gbase  = scn + MAX_JB;                                  // 2KB
            for (int b = blockIdx.x; b < n_pinb; b += NBLK) {                 // ~2 buckets
                const int pbase = b << PINB_SHIFT;
                __syncthreads();           // prior iter staged reads done

                uint2 e[16];
                #pragma unroll
                for (int m = 0; m < 16; ++m)
                    e[m] = ent1[pbase + t + NTHR2 * m];          // 16-deep pipeline
                for (int i = t; i < PINB_SIZE; i += NTHR2) {     // coalesced window
                    float2 p = pos2[pbase + i];
                    win[i] = d ? p.y : p.x;
                }
                if (t < MAX_JB) hist[t] = 0;
                __syncthreads();

                float yv[16]; unsigned rnk[16];
                #pragma unroll
                for (int m = 0; m < 16; ++m)
                    yv[m] = win[e[m].x & (PINB_SIZE - 1)];
                #pragma unroll
                for (int m = 0; m < 16; ++m)
                    rnk[m] = atomicAdd(&hist[e[m].y >> JB_SHIFT], 1u);
                __syncthreads();

                if (t < 64) {              // wave-0 scan, 8 buckets/lane
                    unsigned v[8], s = 0;
                    #pragma unroll
                    for (int i = 0; i < 8; ++i) { v[i] = hist[t * 8 + i]; s += v[i]; }
                    unsigned ex = s;
                    #pragma unroll
                    for (int off = 1; off < 64; off <<= 1) {
                        unsigned u = __shfl_up(ex, off, 64);
                        if (t >= off) ex += u;
                    }
                    ex -= s;
                    #pragma unroll
                    for (int i = 0; i < 8; ++i) { scn[t * 8 + i] = ex; ex += v[i]; }
                }
                __syncthreads();

                for (int q = t; q < n_jb; q += NTHR2)
                    if (hist[q]) gbase[q] = atomicAdd(&cur2[q], hist[q]);
                __syncthreads();

                #pragma unroll
                for (int m = 0; m < 16; ++m)                     // overwrite win
                    staged[scn[e[m].y >> JB_SHIFT] + rnk[m]] =
                        make_uint2(e[m].y, __float_as_uint(yv[m]));
                __syncthreads();

                for (int k = t; k < PINB_SIZE; k += NTHR2) {     // coalesced runs
                    uint2 s2 = staged[k];
                    unsigned jb = s2.x >> JB_SHIFT;
                    unsigned slot = (gbase[jb] + ((unsigned)k - scn[jb])) & (JB_SIZE - 1);
                    ent2d[((size_t)jb << JB_SHIFT) + slot] = s2;
                }
            }
        }
        grid_bar(bar);

        // phase C
        {
            float* ytmp = (float*)smem;                          // 64KB
            const float ig = ig_p[0];
            for (int jb = blockIdx.x; jb < n_jb; jb += NBLK) {   // 1 j-bucket
                const int base_j = jb << JB_SHIFT;
                __syncthreads();
                for (int k = t; k < JB_SIZE; k += NTHR2) {       // coalesced read
                    uint2 e = ent2d[base_j + k];
                    ytmp[e.x & (JB_SIZE - 1)] = __uint_as_float(e.y);
                }
                __syncthreads();

                float val = 0.0f;
                const int bnet = base_j >> 2;
                const float4* y4 = (const float4*)ytmp;
                for (int i = t; i < (JB_SIZE >> 2); i += NTHR2) {
                    float4 p = y4[i];                            // ds_read_b128
                    val += wts[bnet + i] * wa4(p.x, p.y, p.z, p.w, ig);
                }
                #pragma unroll
                for (int off = 32; off > 0; off >>= 1)
                    val += __shfl_down(val, off, 64);
                __syncthreads();           // y4 reads done before partial write
                if ((t & 63) == 0) ytmp[t >> 6] = val;
                __syncthreads();
                if (t == 0) {
                    float s = 0.0f;
                    #pragma unroll
                    for (int w = 0; w < NTHR2 / 64; ++w) s += ytmp[w];
                    atomicAdd(out, s);
                }
            }
        }
    }
}

// ---------------- fallback: proven R1 gather kernel ----------------
__global__ __launch_bounds__(256) void wasll_fallback(
    const float2* __restrict__ pos, const int4* __restrict__ fnp4,
    const float* __restrict__ net_weights, const float* __restrict__ inv_gamma_p,
    const int* __restrict__ slrx_p, const int* __restrict__ slry_p,
    float* __restrict__ out, int num_nets)
{
    const float ig = inv_gamma_p[0];
    const float dx = (slrx_p[0] > 1) ? 1.0f : 0.0f;
    const float dy = (slry_p[0] > 1) ? 1.0f : 0.0f;
    int net = blockIdx.x * blockDim.x + threadIdx.x;
    float val = 0.0f;
    if (net < num_nets) {
        int4 idx = fnp4[net];
        float2 p0 = pos[idx.x], p1 = pos[idx.y], p2 = pos[idx.z], p3 = pos[idx.w];
        val = net_weights[net] * (dx * wa4(p0.x, p1.x, p2.x, p3.x, ig)
                                + dy * wa4(p0.y, p1.y, p2.y, p3.y, ig));
    }
    #pragma unroll
    for (int off = 32; off > 0; off >>= 1) val += __shfl_down(val, off, 64);
    __shared__ float smem[4];
    if ((threadIdx.x & 63) == 0) smem[threadIdx.x >> 6] = val;
    __syncthreads();
    if (threadIdx.x == 0)
        atomicAdd(out, smem[0] + smem[1] + smem[2] + smem[3]);
}

__global__ void zero_out_kernel(float* __restrict__ out) { out[0] = 0.0f; }

extern "C" void kernel_launch(void* const* d_in, const int* in_sizes, int n_in,
                              void* d_out, int out_size, void* d_ws, size_t ws_size,
                              hipStream_t stream) {
    const float* posf        = (const float*)d_in[0];
    const int*   fnp         = (const int*)d_in[1];
    const float* net_weights = (const float*)d_in[4];
    const float* inv_gamma   = (const float*)d_in[7];
    const int*   slrx        = (const int*)d_in[8];
    const int*   slry        = (const int*)d_in[9];
    float*       out         = (float*)d_out;
    const int    N  = in_sizes[4];
    const int    NP = in_sizes[1];

    const int n_pinb = NP >> PINB_SHIFT;
    const int n_jb   = NP >> JB_SHIFT;

    size_t off = 0;
    auto carve = [&](size_t bytes) { size_t o = off; off += (bytes + 255) & ~size_t(255); return o; };
    size_t o_ent1  = carve((size_t)NP * sizeof(uint2));
    size_t o_ent2a = carve((size_t)NP * sizeof(uint2));
    size_t o_cur1  = carve((size_t)MAX_PINB * sizeof(unsigned));
    size_t o_cur2  = carve((size_t)MAX_JB * sizeof(unsigned));
    size_t o_bar   = carve(256);
    size_t core    = off;
    size_t o_ent2b = carve((size_t)NP * sizeof(uint2));  // optional dual half

    const bool ok = (NP == 4 * N) && (NP % JB_SIZE == 0) && (NP > 0) &&
                    (n_pinb <= MAX_PINB) && (n_jb <= MAX_JB) && (core <= ws_size);
    if (!ok) {
        hipLaunchKernelGGL(zero_out_kernel, dim3(1), dim3(1), 0, stream, out);
        const int block = 256, grid = (N + block - 1) / block;
        hipLaunchKernelGGL(wasll_fallback, dim3(grid), dim3(block), 0, stream,
                           (const float2*)posf, (const int4*)fnp, net_weights,
                           inv_gamma, slrx, slry, out, N);
        return;
    }

    const bool dual = (off <= ws_size);
    char* ws = (char*)d_ws;
    uint2*    ent1  = (uint2*)(ws + o_ent1);
    uint2*    ent2a = (uint2*)(ws + o_ent2a);
    uint2*    ent2b = dual ? (uint2*)(ws + o_ent2b) : ent2a;
    unsigned* cur1  = (unsigned*)(ws + o_cur1);
    unsigned* cur2  = (unsigned*)(ws + o_cur2);
    unsigned* bar   = (unsigned*)(ws + o_bar);

    // only the barrier counter needs a defined start (cursors are
    // garbage-rotation safe); 2 dispatches total.
    hipMemsetAsync(bar, 0, 256, stream);
    hipLaunchKernelGGL(fused_wasll, dim3(NBLK), dim3(NTHR2), 0, stream,
                       (const int4*)fnp, (const float2*)posf, net_weights,
                       inv_gamma, slrx, slry, NP, n_pinb, n_jb,
                       ent1, ent2a, ent2b, cur1, cur2, bar, out);
}